// Round 11
// baseline (775.983 us; speedup 1.0000x reference)
//
#include <hip/hip_runtime.h>

#define TS 512
#define LOG2E 1.4426950408889634f

typedef _Float16 f16x8 __attribute__((ext_vector_type(8)));
typedef float f32x4 __attribute__((ext_vector_type(4)));
typedef unsigned int u32;

#define MFMA16(a, b, c) __builtin_amdgcn_mfma_f32_16x16x32_f16((a), (b), (c), 0, 0, 0)

// ws (f16), all weight values pre-scaled by log2e:
//  R1 [0,65536):      L1 hh frags [(wi*16+g*4+kt)*512 + l*8 + j] = w_hh1[n][k]
//                       n = g*128+wi*16+(l&15), k = kt*32+(l>>4)*8+j   (wi=0..7)
//  R2 [65536,81920):  L1 x/bias frags [(wi*4+g)*512 + l*8 + j]: k-slot s=(l>>4)*8+j:
//                       s==0 -> b_ih1+b_hh1 at n;  s==1 -> w_ih1[n];  else 0
//  R3 [81920,131072): L2 frags [(w2*24+g*6+kt)*512 + l*8 + j] = W2cat[n][k]
//                       n = g*64+w2*16+(l&15), W2cat=[w_ih2 | w_hh2]  (w2=0..3)
__global__ __launch_bounds__(512) void prep(
    const float* __restrict__ w_hh1, const float* __restrict__ w_ih1,
    const float* __restrict__ b_ih1, const float* __restrict__ b_hh1,
    const float* __restrict__ w_ih2, const float* __restrict__ w_hh2,
    _Float16* __restrict__ wsh)
{
  int idx = blockIdx.x * 512 + threadIdx.x;   // 131072 total
  int l = (idx >> 3) & 63, j = idx & 7;
  float v;
  if (idx < 65536) {
    int f = idx >> 9;
    int wi = f >> 4, g = (f >> 2) & 3, kt = f & 3;
    int n = g * 128 + wi * 16 + (l & 15);
    int k = kt * 32 + (l >> 4) * 8 + j;
    v = w_hh1[n * 128 + k];
  } else if (idx < 81920) {
    int f = (idx - 65536) >> 9;
    int wi = f >> 2, g = f & 3;
    int n = g * 128 + wi * 16 + (l & 15);
    int s = (l >> 4) * 8 + j;
    v = (s == 0) ? (b_ih1[n] + b_hh1[n]) : ((s == 1) ? w_ih1[n] : 0.0f);
  } else {
    int f = (idx - 81920) >> 9;
    int w2 = f / 24, rem = f % 24, g = rem / 6, kt = rem % 6;
    int n = g * 64 + w2 * 16 + (l & 15);
    int k = kt * 32 + (l >> 4) * 8 + j;
    v = (k < 128) ? w_ih2[n * 128 + k] : w_hh2[n * 64 + (k - 128)];
  }
  wsh[idx] = (_Float16)(v * LOG2E);
}

__device__ __forceinline__ float rcpf_(float x) { return __builtin_amdgcn_rcpf(x); }
__device__ __forceinline__ float sig_s(float s)  { return rcpf_(1.0f + exp2f(-s)); }
__device__ __forceinline__ float tanh_s(float s) { return 1.0f - 2.0f * rcpf_(exp2f(s + s) + 1.0f); }
__device__ __forceinline__ float tanh_c(float c) { return 1.0f - 2.0f * rcpf_(exp2f(c * (2.0f * LOG2E)) + 1.0f); }

// HC plane (fragment-linear): plane = 6 chunks of 1KB; chunk kt covers k in [kt*32,kt*32+32).
// Element (row r, k): lane = r + ((k>>3)&3)*16, byte = kt*1024 + lane*16 + (k&7)*2.
// k 0..127 = h1 units, k 128..191 = h2 units. Rows 8..15 permanently zero.
// Interval i: L1 (waves 0-7) computes h1[i]: reads PL(i-1) ch0-3, writes PL(i) ch0-3.
//             L2 (waves 8-11) computes h2[i-1]: reads PL(i-1) ch0-3 + PL(i) ch4-5,
//                                               writes PL(i-1) ch4-5. Disjoint; 1 barrier.
// Epilogue: NO cross-lane exchange. Lanes with q<2 own all 4 C-rows (MFMA rows
// 4q+r, r=0..3) of their column; q>=2 lanes idle (exec-masked). Bit-exact vs
// the shfl_xor formulation: same acc bits, same math, same store addresses.

#define L1_BODY(I, PI, PIM)                                                    \
  {                                                                            \
    union { u32 uu[4]; f16x8 vv; } a6u;                                        \
    a6u.uu[0] = xpk[xrow + (I)];                                               \
    a6u.uu[1] = 0u; a6u.uu[2] = 0u; a6u.uu[3] = 0u;                            \
    f32x4 acc[4];                                                              \
    _Pragma("unroll") for (int g = 0; g < 4; ++g)                              \
      acc[g] = MFMA16(a6u.vv, BF[16 + g], zq);                                 \
    _Pragma("unroll") for (int kt = 0; kt < 4; ++kt) {                         \
      f16x8 av = *(const f16x8*)((PIM) + lofs + kt * 1024);                    \
      _Pragma("unroll") for (int g = 0; g < 4; ++g)                            \
        acc[g] = MFMA16(av, BF[g * 4 + kt], acc[g]);                           \
    }                                                                          \
    if (q < 2) {                                                               \
      _Pragma("unroll") for (int r = 0; r < 4; ++r) {                          \
        const float ii = sig_s(acc[0][r]), ff = sig_s(acc[1][r]);              \
        const float gv = tanh_s(acc[2][r]), oo = sig_s(acc[3][r]);             \
        cst[r] = fmaf(ff, cst[r], ii * gv);                                    \
        const float hv = oo * tanh_c(cst[r]);                                  \
        *(_Float16*)((PI) + ha0 + r * 16) = (_Float16)hv;                      \
      }                                                                        \
    }                                                                          \
  }

#define L2_BODY(PI, PIM, WRLDS, WRF)                                           \
  {                                                                            \
    f32x4 acc[4];                                                              \
    {                                                                          \
      f16x8 ev = *(const f16x8*)((PIM) + lofs);                                \
      _Pragma("unroll") for (int g = 0; g < 4; ++g)                            \
        acc[g] = MFMA16(ev, BF[g * 6], zq);                                    \
    }                                                                          \
    _Pragma("unroll") for (int kt = 1; kt < 4; ++kt) {                         \
      f16x8 ev = *(const f16x8*)((PIM) + lofs + kt * 1024);                    \
      _Pragma("unroll") for (int g = 0; g < 4; ++g)                            \
        acc[g] = MFMA16(ev, BF[g * 6 + kt], acc[g]);                           \
    }                                                                          \
    _Pragma("unroll") for (int kt = 4; kt < 6; ++kt) {                         \
      f16x8 ev = *(const f16x8*)((PI) + lofs + kt * 1024);                     \
      _Pragma("unroll") for (int g = 0; g < 4; ++g)                            \
        acc[g] = MFMA16(ev, BF[g * 6 + kt], acc[g]);                           \
    }                                                                          \
    if (q < 2) {                                                               \
      _Pragma("unroll") for (int r = 0; r < 4; ++r) {                          \
        const float s0 = acc[0][r] + biv[0], s1 = acc[1][r] + biv[1];          \
        const float s2 = acc[2][r] + biv[2], s3 = acc[3][r] + biv[3];          \
        const float ii = sig_s(s0), ff = sig_s(s1);                            \
        const float gv = tanh_s(s2), oo = sig_s(s3);                           \
        cst[r] = fmaf(ff, cst[r], ii * gv);                                    \
        const float hv = oo * tanh_c(cst[r]);                                  \
        if (WRLDS) *(_Float16*)((PIM) + ha0 + r * 16) = (_Float16)hv;          \
        if (WRF) h2f[(q << 2) + r][u2] = hv;                                   \
      }                                                                        \
    }                                                                          \
  }

__global__ __launch_bounds__(768, 3) void lstm_mfma(
    const float* __restrict__ x,
    const float* __restrict__ b_ih2, const float* __restrict__ b_hh2,
    const float* __restrict__ w_d1, const float* __restrict__ b_d1,
    const float* __restrict__ w_d2, const float* __restrict__ b_d2,
    const _Float16* __restrict__ wsh,
    float* __restrict__ out)
{
  __shared__ __align__(16) _Float16 HC[2 * 3072];   // 12 KB, two planes
  __shared__ __align__(16) u32 xpk[8 * 516];        // 16.5 KB: packed (1.0h, x_f16)
  __shared__ float h2f[8][65];
  __shared__ float dh[200];

  const int tid = threadIdx.x;
  const int w   = tid >> 6;        // wave 0..11
  const int l   = tid & 63;
  const int col = l & 15;
  const int q   = l >> 4;
  const int wg  = (w < 8) ? 0 : 1; // 0 = L1, 1 = L2
  const int w2  = w - 8;
  const int r0  = blockIdx.x * 8;
  const int lofs = l * 16;
  const int xrow = (l & 7) * 516;
  const int u2  = (wg == 1) ? (w2 * 16 + col) : 0;

  f16x8 BF[24];                    // L1: 16 hh + 4 x/bias; L2: 24
  float biv[4] = {0.f, 0.f, 0.f, 0.f};
  int ha0;

  if (wg == 0) {
    #pragma unroll
    for (int f = 0; f < 16; ++f)
      BF[f] = *(const f16x8*)(wsh + (w * 16 + f) * 512 + l * 8);
    #pragma unroll
    for (int g = 0; g < 4; ++g)
      BF[16 + g] = *(const f16x8*)(wsh + 65536 + (w * 4 + g) * 512 + l * 8);
    const int u = w * 16 + col;    // h1 unit
    ha0 = (u >> 5) * 1024 + ((q & 1) * 4 + ((u >> 3) & 3) * 16) * 16 + (u & 7) * 2;
  } else {
    #pragma unroll
    for (int f = 0; f < 24; ++f)
      BF[f] = *(const f16x8*)(wsh + 81920 + (w2 * 24 + f) * 512 + l * 8);
    #pragma unroll
    for (int g = 0; g < 4; ++g)
      biv[g] = (b_ih2[g * 64 + u2] + b_hh2[g * 64 + u2]) * LOG2E;
    ha0 = (4 + (u2 >> 5)) * 1024 + ((q & 1) * 4 + ((u2 >> 3) & 3) * 16) * 16 + (u2 & 7) * 2;
  }

  // x -> packed LDS table; zero both h planes
  for (int i = tid; i < 4096; i += 768) {
    int r = i >> 9, t = i & 511;
    union { _Float16 h; unsigned short s; } cv;
    cv.h = (_Float16)x[(r0 + r) * 512 + t];
    xpk[r * 516 + t] = 0x3C00u | ((u32)cv.s << 16);
  }
  for (int i = tid; i < 3072; i += 768) ((u32*)HC)[i] = 0u;

  float cst[4] = {0.f, 0.f, 0.f, 0.f};
  const f32x4 zq = {0.f, 0.f, 0.f, 0.f};
  char* const hcb = (char*)HC;
  __syncthreads();

  #pragma unroll 1
  for (int i = 0; i < TS; i += 2) {
    // interval i (even): PL(i)=plane0, PL(i-1)=plane1
    if (wg == 0)      { L1_BODY(i, hcb, hcb + 6144) }
    else if (i > 0)   { L2_BODY(hcb, hcb + 6144, 1, 0) }
    __syncthreads();
    // interval i+1 (odd): PL(i+1)=plane1, PL(i)=plane0
    if (wg == 0)      { L1_BODY(i + 1, hcb + 6144, hcb) }
    else              { L2_BODY(hcb + 6144, hcb, 1, 0) }
    __syncthreads();
  }
  // interval TS (even): L2 computes h2[TS-1]; store to h2f only
  if (wg == 1)        { L2_BODY(hcb, hcb + 6144, 0, 1) }
  __syncthreads();

  // ---- dense head (fp32) ----
  if (tid < 200) {
    int r = tid / 25, d = tid - r * 25;
    float acc = b_d1[d];
    #pragma unroll
    for (int uu = 0; uu < 64; ++uu) acc = fmaf(h2f[r][uu], w_d1[d * 64 + uu], acc);
    dh[tid] = acc;
  }
  __syncthreads();
  if (tid < 8) {
    float y = b_d2[0];
    #pragma unroll
    for (int d = 0; d < 25; ++d) y = fmaf(dh[tid * 25 + d], w_d2[d], y);
    out[r0 + tid] = y;
  }
}

extern "C" void kernel_launch(void* const* d_in, const int* in_sizes, int n_in,
                              void* d_out, int out_size, void* d_ws, size_t ws_size,
                              hipStream_t stream) {
  (void)in_sizes; (void)n_in; (void)out_size; (void)ws_size;
  const float* x     = (const float*)d_in[0];
  const float* w_ih1 = (const float*)d_in[1];
  const float* w_hh1 = (const float*)d_in[2];
  const float* b_ih1 = (const float*)d_in[3];
  const float* b_hh1 = (const float*)d_in[4];
  const float* w_ih2 = (const float*)d_in[5];
  const float* w_hh2 = (const float*)d_in[6];
  const float* b_ih2 = (const float*)d_in[7];
  const float* b_hh2 = (const float*)d_in[8];
  const float* w_d1  = (const float*)d_in[9];
  const float* b_d1  = (const float*)d_in[10];
  const float* w_d2  = (const float*)d_in[11];
  const float* b_d2  = (const float*)d_in[12];
  _Float16* wsh = (_Float16*)d_ws;
  float* outp = (float*)d_out;

  prep<<<256, 512, 0, stream>>>(w_hh1, w_ih1, b_ih1, b_hh1, w_ih2, w_hh2, wsh);
  lstm_mfma<<<256, 768, 0, stream>>>(x, b_ih2, b_hh2, w_d1, b_d1, w_d2, b_d2, wsh, outp);
}

// Round 12
// 571.225 us; speedup vs baseline: 1.3585x; 1.3585x over previous
//
#include <hip/hip_runtime.h>

#define TS 512
#define LOG2E 1.4426950408889634f

typedef _Float16 f16x8 __attribute__((ext_vector_type(8)));
typedef float f32x4 __attribute__((ext_vector_type(4)));
typedef unsigned int u32;

#define MFMA16(a, b, c) __builtin_amdgcn_mfma_f32_16x16x32_f16((a), (b), (c), 0, 0, 0)

// ws (f16), all weight values pre-scaled by log2e:
//  R1 [0,65536):      L1 hh frags [(wi*16+g*4+kt)*512 + l*8 + j] = w_hh1[n][k]
//                       n = g*128+wi*16+(l&15), k = kt*32+(l>>4)*8+j   (wi=0..7)
//  R2 [65536,81920):  L1 x/bias frags [(wi*4+g)*512 + l*8 + j]: k-slot s=(l>>4)*8+j:
//                       s==0 -> b_ih1+b_hh1 at n;  s==1 -> w_ih1[n];  else 0
//  R3 [81920,131072): L2 frags [(w2*24+g*6+kt)*512 + l*8 + j] = W2cat[n][k]
//                       n = g*64+w2*16+(l&15), W2cat=[w_ih2 | w_hh2]  (w2=0..3)
__global__ __launch_bounds__(512) void prep(
    const float* __restrict__ w_hh1, const float* __restrict__ w_ih1,
    const float* __restrict__ b_ih1, const float* __restrict__ b_hh1,
    const float* __restrict__ w_ih2, const float* __restrict__ w_hh2,
    _Float16* __restrict__ wsh)
{
  int idx = blockIdx.x * 512 + threadIdx.x;   // 131072 total
  int l = (idx >> 3) & 63, j = idx & 7;
  float v;
  if (idx < 65536) {
    int f = idx >> 9;
    int wi = f >> 4, g = (f >> 2) & 3, kt = f & 3;
    int n = g * 128 + wi * 16 + (l & 15);
    int k = kt * 32 + (l >> 4) * 8 + j;
    v = w_hh1[n * 128 + k];
  } else if (idx < 81920) {
    int f = (idx - 65536) >> 9;
    int wi = f >> 2, g = f & 3;
    int n = g * 128 + wi * 16 + (l & 15);
    int s = (l >> 4) * 8 + j;
    v = (s == 0) ? (b_ih1[n] + b_hh1[n]) : ((s == 1) ? w_ih1[n] : 0.0f);
  } else {
    int f = (idx - 81920) >> 9;
    int w2 = f / 24, rem = f % 24, g = rem / 6, kt = rem % 6;
    int n = g * 64 + w2 * 16 + (l & 15);
    int k = kt * 32 + (l >> 4) * 8 + j;
    v = (k < 128) ? w_ih2[n * 128 + k] : w_hh2[n * 64 + (k - 128)];
  }
  wsh[idx] = (_Float16)(v * LOG2E);
}

__device__ __forceinline__ float rcpf_(float x) { return __builtin_amdgcn_rcpf(x); }

// HC plane (fragment-linear): plane = 6 chunks of 1KB; chunk kt covers k in [kt*32,kt*32+32).
// Element (row r, k): lane = r + ((k>>3)&3)*16, byte = kt*1024 + lane*16 + (k&7)*2.
// k 0..127 = h1 units, k 128..191 = h2 units. Rows 8..15 permanently zero.
// Interval i: L1 (waves 0-7) computes h1[i]: reads PL(i-1) ch0-3, writes PL(i) ch0-3.
//             L2 (waves 8-11) computes h2[i-1]: reads PL(i-1) ch0-3 + PL(i) ch4-5,
//                                               writes PL(i-1) ch4-5. Disjoint; 1 barrier.

// fused-rcp epilogue (verified numerics-safe in R7: absmax identical 2.441406e-4):
// i*g and o*tanh(c) each share one rcp; tanh(c) exponent clamped at 120 so the
// fused form stays finite if c drifts large. 4 exp2 + 3 rcp per row (was 5+5).
#define EPILOGUE(RR, HV)                                                       \
      const float e0 = exp2f(-sv[0]);                                          \
      const float E2 = exp2f(sv[2] + sv[2]);                                   \
      const float ig = (E2 - 1.0f) * rcpf_((1.0f + e0) * (E2 + 1.0f));         \
      const float ff = rcpf_(1.0f + exp2f(-sv[1]));                            \
      cst[RR] = fmaf(ff, cst[RR], ig);                                         \
      const float tc = fminf(cst[RR] * (2.0f * LOG2E), 120.0f);                \
      const float Ec = exp2f(tc);                                              \
      const float e3 = exp2f(-sv[3]);                                          \
      const float HV = (Ec - 1.0f) * rcpf_((1.0f + e3) * (Ec + 1.0f));

#define L1_BODY(I, PI, PIM)                                                    \
  {                                                                            \
    union { u32 uu[4]; f16x8 vv; } a6u;                                        \
    a6u.uu[0] = xpk[xrow + (I)];                                               \
    a6u.uu[1] = 0u; a6u.uu[2] = 0u; a6u.uu[3] = 0u;                            \
    f32x4 acc[4];                                                              \
    _Pragma("unroll") for (int g = 0; g < 4; ++g)                              \
      acc[g] = MFMA16(a6u.vv, BF[16 + g], zq);                                 \
    _Pragma("unroll") for (int kt = 0; kt < 4; ++kt) {                         \
      f16x8 av = *(const f16x8*)((PIM) + lofs + kt * 1024);                    \
      _Pragma("unroll") for (int g = 0; g < 4; ++g)                            \
        acc[g] = MFMA16(av, BF[g * 4 + kt], acc[g]);                           \
    }                                                                          \
    _Pragma("unroll") for (int rr = 0; rr < 2; ++rr) {                         \
      float sv[4];                                                             \
      _Pragma("unroll") for (int g = 0; g < 4; ++g) {                          \
        const float oth = __shfl_xor(acc[g][2 + rr], 32, 64);                  \
        sv[g] = up ? oth : acc[g][rr];                                         \
      }                                                                        \
      EPILOGUE(rr, hv)                                                         \
      *(_Float16*)((PI) + ha[rr]) = (_Float16)hv;                              \
    }                                                                          \
  }

#define L2_BODY(PI, PIM, WRLDS, WRF)                                           \
  {                                                                            \
    f32x4 acc[4];                                                              \
    {                                                                          \
      f16x8 ev = *(const f16x8*)((PIM) + lofs);                                \
      _Pragma("unroll") for (int g = 0; g < 4; ++g)                            \
        acc[g] = MFMA16(ev, BF[g * 6], zq);                                    \
    }                                                                          \
    _Pragma("unroll") for (int kt = 1; kt < 4; ++kt) {                         \
      f16x8 ev = *(const f16x8*)((PIM) + lofs + kt * 1024);                    \
      _Pragma("unroll") for (int g = 0; g < 4; ++g)                            \
        acc[g] = MFMA16(ev, BF[g * 6 + kt], acc[g]);                           \
    }                                                                          \
    _Pragma("unroll") for (int kt = 4; kt < 6; ++kt) {                         \
      f16x8 ev = *(const f16x8*)((PI) + lofs + kt * 1024);                     \
      _Pragma("unroll") for (int g = 0; g < 4; ++g)                            \
        acc[g] = MFMA16(ev, BF[g * 6 + kt], acc[g]);                           \
    }                                                                          \
    _Pragma("unroll") for (int rr = 0; rr < 2; ++rr) {                         \
      float sv[4];                                                             \
      _Pragma("unroll") for (int g = 0; g < 4; ++g) {                          \
        const float oth = __shfl_xor(acc[g][2 + rr], 32, 64);                  \
        sv[g] = (up ? oth : acc[g][rr]) + biv[g];                              \
      }                                                                        \
      EPILOGUE(rr, hv)                                                         \
      if (WRLDS) *(_Float16*)((PIM) + ha[rr]) = (_Float16)hv;                  \
      if (WRF) h2f[rb + rr][u2] = hv;                                          \
    }                                                                          \
  }

__global__ __launch_bounds__(768, 3) void lstm_mfma(
    const float* __restrict__ x,
    const float* __restrict__ b_ih2, const float* __restrict__ b_hh2,
    const float* __restrict__ w_d1, const float* __restrict__ b_d1,
    const float* __restrict__ w_d2, const float* __restrict__ b_d2,
    const _Float16* __restrict__ wsh,
    float* __restrict__ out)
{
  __shared__ __align__(16) _Float16 HC[2 * 3072];   // 12 KB, two planes
  __shared__ __align__(16) u32 xpk[8 * 516];        // 16.5 KB: packed (1.0h, x_f16)
  __shared__ float h2f[8][65];
  __shared__ float dh[200];

  const int tid = threadIdx.x;
  const int w   = tid >> 6;        // wave 0..11
  const int l   = tid & 63;
  const int col = l & 15;
  const int q   = l >> 4;
  const int up  = q >> 1;
  const int rb  = 4 * (q & 1) + 2 * up;   // rows {rb, rb+1}
  const int wg  = (w < 8) ? 0 : 1;        // 0 = L1, 1 = L2
  const int w2  = w - 8;
  const int r0  = blockIdx.x * 8;
  const int lofs = l * 16;
  const int xrow = (l & 7) * 516;
  const int u2  = (wg == 1) ? (w2 * 16 + col) : 0;

  f16x8 BF[24];                    // L1: 16 hh + 4 x/bias; L2: 24
  float biv[4] = {0.f, 0.f, 0.f, 0.f};
  int ha[2];

  if (wg == 0) {
    #pragma unroll
    for (int f = 0; f < 16; ++f)
      BF[f] = *(const f16x8*)(wsh + (w * 16 + f) * 512 + l * 8);
    #pragma unroll
    for (int g = 0; g < 4; ++g)
      BF[16 + g] = *(const f16x8*)(wsh + 65536 + (w * 4 + g) * 512 + l * 8);
    const int u = w * 16 + col;    // h1 unit
    #pragma unroll
    for (int rr = 0; rr < 2; ++rr)
      ha[rr] = (u >> 5) * 1024 + ((rb + rr) + ((u >> 3) & 3) * 16) * 16 + (u & 7) * 2;
  } else {
    #pragma unroll
    for (int f = 0; f < 24; ++f)
      BF[f] = *(const f16x8*)(wsh + 81920 + (w2 * 24 + f) * 512 + l * 8);
    #pragma unroll
    for (int g = 0; g < 4; ++g)
      biv[g] = (b_ih2[g * 64 + u2] + b_hh2[g * 64 + u2]) * LOG2E;
    #pragma unroll
    for (int rr = 0; rr < 2; ++rr)
      ha[rr] = (4 + (u2 >> 5)) * 1024 + ((rb + rr) + ((u2 >> 3) & 3) * 16) * 16 + (u2 & 7) * 2;
  }

  // x -> packed LDS table; zero both h planes
  for (int i = tid; i < 4096; i += 768) {
    int r = i >> 9, t = i & 511;
    union { _Float16 h; unsigned short s; } cv;
    cv.h = (_Float16)x[(r0 + r) * 512 + t];
    xpk[r * 516 + t] = 0x3C00u | ((u32)cv.s << 16);
  }
  for (int i = tid; i < 3072; i += 768) ((u32*)HC)[i] = 0u;

  float cst[2] = {0.f, 0.f};
  const f32x4 zq = {0.f, 0.f, 0.f, 0.f};
  char* const hcb = (char*)HC;
  __syncthreads();

  #pragma unroll 1
  for (int i = 0; i < TS; i += 2) {
    // interval i (even): PL(i)=plane0, PL(i-1)=plane1
    if (wg == 0)      { L1_BODY(i, hcb, hcb + 6144) }
    else if (i > 0)   { L2_BODY(hcb, hcb + 6144, 1, 0) }
    __syncthreads();
    // interval i+1 (odd): PL(i+1)=plane1, PL(i)=plane0
    if (wg == 0)      { L1_BODY(i + 1, hcb + 6144, hcb) }
    else              { L2_BODY(hcb + 6144, hcb, 1, 0) }
    __syncthreads();
  }
  // interval TS (even): L2 computes h2[TS-1]; store to h2f only
  if (wg == 1)        { L2_BODY(hcb, hcb + 6144, 0, 1) }
  __syncthreads();

  // ---- dense head (fp32) ----
  if (tid < 200) {
    int r = tid / 25, d = tid - r * 25;
    float acc = b_d1[d];
    #pragma unroll
    for (int uu = 0; uu < 64; ++uu) acc = fmaf(h2f[r][uu], w_d1[d * 64 + uu], acc);
    dh[tid] = acc;
  }
  __syncthreads();
  if (tid < 8) {
    float y = b_d2[0];
    #pragma unroll
    for (int d = 0; d < 25; ++d) y = fmaf(dh[tid * 25 + d], w_d2[d], y);
    out[r0 + tid] = y;
  }
}

extern "C" void kernel_launch(void* const* d_in, const int* in_sizes, int n_in,
                              void* d_out, int out_size, void* d_ws, size_t ws_size,
                              hipStream_t stream) {
  (void)in_sizes; (void)n_in; (void)out_size; (void)ws_size;
  const float* x     = (const float*)d_in[0];
  const float* w_ih1 = (const float*)d_in[1];
  const float* w_hh1 = (const float*)d_in[2];
  const float* b_ih1 = (const float*)d_in[3];
  const float* b_hh1 = (const float*)d_in[4];
  const float* w_ih2 = (const float*)d_in[5];
  const float* w_hh2 = (const float*)d_in[6];
  const float* b_ih2 = (const float*)d_in[7];
  const float* b_hh2 = (const float*)d_in[8];
  const float* w_d1  = (const float*)d_in[9];
  const float* b_d1  = (const float*)d_in[10];
  const float* w_d2  = (const float*)d_in[11];
  const float* b_d2  = (const float*)d_in[12];
  _Float16* wsh = (_Float16*)d_ws;
  float* outp = (float*)d_out;

  prep<<<256, 512, 0, stream>>>(w_hh1, w_ih1, b_ih1, b_hh1, w_ih2, w_hh2, wsh);
  lstm_mfma<<<256, 768, 0, stream>>>(x, b_ih2, b_hh2, w_d1, b_d1, w_d2, b_d2, wsh, outp);
}